// Round 1
// baseline (154.432 us; speedup 1.0000x reference)
//
#include <hip/hip_runtime.h>

// Reference collapses to: val = sum(W2 @ relu(W1[:,0] + b1) + b2), broadcast
// to [B=8, OC=64, H=224, W=224] fp32.
//
// Input order: x[unused], W1[256*65536], b1[256], W2[64*256], b2[64], params[unused]

#define DIM   65536
#define HID   256
#define OC_N  64
#define OUT_N (8ULL * 64 * 224 * 224)  // 25,690,112 floats, divisible by 4

__global__ void compute_val_kernel(const float* __restrict__ W1,
                                   const float* __restrict__ b1,
                                   const float* __restrict__ W2,
                                   const float* __restrict__ b2,
                                   float* __restrict__ ws) {
    const int h = threadIdx.x;  // 0..255 == HID

    // hidden[h] = relu(W1[h, 0] + b1[h]); W1 row-major [HID, DIM] -> stride DIM
    float hidden = W1[(size_t)h * DIM] + b1[h];
    hidden = hidden > 0.0f ? hidden : 0.0f;

    // colsum[h] = sum_oc W2[oc, h]; consecutive threads read consecutive addrs
    float colsum = 0.0f;
#pragma unroll
    for (int oc = 0; oc < OC_N; ++oc) {
        colsum += W2[oc * HID + h];
    }

    float partial = hidden * colsum + (h < OC_N ? b2[h] : 0.0f);

    // wave64 shuffle reduce
#pragma unroll
    for (int off = 32; off > 0; off >>= 1) {
        partial += __shfl_down(partial, off, 64);
    }

    __shared__ float smem[4];
    if ((h & 63) == 0) smem[h >> 6] = partial;
    __syncthreads();
    if (h == 0) {
        ws[0] = smem[0] + smem[1] + smem[2] + smem[3];
    }
}

__global__ void fill_out_kernel(const float* __restrict__ ws,
                                float4* __restrict__ out) {
    const float v = ws[0];  // broadcast load, L1/L2 hit for all waves
    const float4 v4 = make_float4(v, v, v, v);
    const size_t n4 = OUT_N / 4;  // 6,422,528
    const size_t stride = (size_t)gridDim.x * blockDim.x;
    for (size_t i = (size_t)blockIdx.x * blockDim.x + threadIdx.x; i < n4; i += stride) {
        out[i] = v4;
    }
}

extern "C" void kernel_launch(void* const* d_in, const int* in_sizes, int n_in,
                              void* d_out, int out_size, void* d_ws, size_t ws_size,
                              hipStream_t stream) {
    const float* W1 = (const float*)d_in[1];
    const float* b1 = (const float*)d_in[2];
    const float* W2 = (const float*)d_in[3];
    const float* b2 = (const float*)d_in[4];
    float* out = (float*)d_out;
    float* ws  = (float*)d_ws;

    compute_val_kernel<<<1, 256, 0, stream>>>(W1, b1, W2, b2, ws);

    // 2048 blocks x 256 threads: ~8 blocks/CU, grid-stride float4 fill
    fill_out_kernel<<<2048, 256, 0, stream>>>(ws, (float4*)out);
}